// Round 2
// baseline (160.638 us; speedup 1.0000x reference)
//
#include <hip/hip_runtime.h>
#include <hip/hip_bf16.h>

// KAN linear as GEMM: M=8192 tokens, N=512 outputs, K=4096 (512 inputs x 8 basis feats;
// basis_0==1 folded into bias). A generated once to ws; m97-style MFMA GEMM w/ split-K.
#define IN_FEAT 512
#define OUT_FEAT 512
#define NTOK 8192
#define KDIM 4096

typedef short bf16x8 __attribute__((ext_vector_type(8)));
typedef float f32x4 __attribute__((ext_vector_type(4)));

static __device__ inline short f2bf(float f) {
    union { float f; unsigned u; } v; v.f = f;
    unsigned u = v.u;
    u += 0x7fffu + ((u >> 16) & 1u);   // RNE
    return (short)(u >> 16);
}

static __device__ inline void gload_lds16(const short* g, short* l) {
    __builtin_amdgcn_global_load_lds(
        (const __attribute__((address_space(1))) unsigned int*)g,
        (__attribute__((address_space(3))) unsigned int*)l,
        16, 0, 0);
}

// ---------------- prep: W bf16 [512 x 4096] + folded bias ----------------
__global__ __launch_bounds__(256) void kan_prep(
    const float* __restrict__ coeff, const float* __restrict__ scale_base,
    const float* __restrict__ scale_spline, const float* __restrict__ base_bias,
    short* __restrict__ Wb, float* __restrict__ bias)
{
    int o = blockIdx.x;
    int tid = threadIdx.x;
    float local = 0.f;
#pragma unroll
    for (int rep = 0; rep < 2; ++rep) {
        int i = tid + rep * 256;
        size_t oi = (size_t)o * IN_FEAT + i;
        const float4* c4 = (const float4*)(coeff + oi * 8);
        float4 ca = c4[0], cb = c4[1];
        float ss = scale_spline[oi];
        float sb = scale_base[oi];
        local += base_bias[oi] + ss * ca.x;
        bf16x8 w;
        w[0] = f2bf(sb);
        w[1] = f2bf(ss * ca.y); w[2] = f2bf(ss * ca.z); w[3] = f2bf(ss * ca.w);
        w[4] = f2bf(ss * cb.x); w[5] = f2bf(ss * cb.y); w[6] = f2bf(ss * cb.z);
        w[7] = f2bf(ss * cb.w);
        *(bf16x8*)(Wb + (size_t)o * KDIM + (size_t)i * 8) = w;
    }
    __shared__ float red[4];
    for (int off = 32; off > 0; off >>= 1) local += __shfl_down(local, off, 64);
    int lane = tid & 63, wv = tid >> 6;
    if (lane == 0) red[wv] = local;
    __syncthreads();
    if (tid == 0) bias[o] = red[0] + red[1] + red[2] + red[3];
}

// ---------------- A-gen: x -> A [8192 x 4096] bf16, done ONCE ----------------
__global__ __launch_bounds__(256) void kan_agen(
    const float* __restrict__ x, short* __restrict__ A)
{
    int idx = blockIdx.x * 256 + threadIdx.x;   // token*512 + input
    float xv = x[idx];
    float xc = fminf(fmaxf(xv, -1.f), 1.f);
    float base = xc / (1.f + __expf(-xc));
    bf16x8 fr;
    fr[0] = f2bf(base);
    float t = xc;
    fr[1] = f2bf(t);
#pragma unroll
    for (int f = 2; f < 8; ++f) { t = 2.f * xc * t - 1.f; fr[f] = f2bf(t); }
    *(bf16x8*)(A + (size_t)idx * 8) = fr;      // 16B/lane, coalesced
}

// ---------------- init: out[n,o] = bias[o] ----------------
__global__ __launch_bounds__(256) void kan_init_out(
    const float* __restrict__ bias, float* __restrict__ out)
{
    int idx = blockIdx.x * 256 + threadIdx.x;   // float4 index
    int o4 = idx & (OUT_FEAT / 4 - 1);
    ((float4*)out)[idx] = ((const float4*)bias)[o4];
}

// ---------------- GEMM: 128x128 tile, BK=64, split-K=2, XOR-swizzled LDS ----------------
#define GBM 128
#define GBN 128
#define GBK 64

__global__ __launch_bounds__(256) void kan_gemm2(
    const short* __restrict__ A, const short* __restrict__ Wb,
    float* __restrict__ out)
{
    __shared__ __align__(16) short As[GBM * GBK];
    __shared__ __align__(16) short Bs[GBN * GBK];

    int tid = threadIdx.x;
    int nb = blockIdx.x, mb = blockIdx.y, ks = blockIdx.z;
    int m0 = mb * GBM, o0 = nb * GBN, k0 = ks * (KDIM / 2);

    int lane = tid & 63, wv = tid >> 6;
    int wm = wv >> 1, wn = wv & 1;          // 2x2 waves, 64x64 tile each
    int qd = lane >> 4, ln15 = lane & 15;

    f32x4 acc[4][4];
#pragma unroll
    for (int a = 0; a < 4; ++a)
#pragma unroll
        for (int b = 0; b < 4; ++b) acc[a][b] = (f32x4)0.f;

    // DMA staging: wave wv stages rows [wv*32, wv*32+32) in 4 calls of 8 rows.
    // LDS dest = uniform base + lane*16 -> row j*8+(lane>>3), phys chunk lane&7.
    // XOR swizzle: logical chunk stored at phys p for row r is c = p ^ (r&7).
    int rg = lane >> 3;                     // 0..7 row within 8-row group
    int c_log = (lane & 7) ^ rg;            // logical 16B chunk this lane fetches
    const short* Ag = A  + (size_t)(m0 + wv * 32 + rg) * KDIM + k0 + c_log * 8;
    const short* Bg = Wb + (size_t)(o0 + wv * 32 + rg) * KDIM + k0 + c_log * 8;

    for (int it = 0; it < (KDIM / 2) / GBK; ++it) {   // 32 iters
        const short* a_it = Ag + it * GBK;
        const short* b_it = Bg + it * GBK;
#pragma unroll
        for (int j = 0; j < 4; ++j)
            gload_lds16(a_it + (size_t)j * 8 * KDIM, &As[(wv * 32 + j * 8) * GBK]);
#pragma unroll
        for (int j = 0; j < 4; ++j)
            gload_lds16(b_it + (size_t)j * 8 * KDIM, &Bs[(wv * 32 + j * 8) * GBK]);
        __syncthreads();

#pragma unroll
        for (int kq = 0; kq < 2; ++kq) {
            bf16x8 af[4], bf[4];
#pragma unroll
            for (int fm = 0; fm < 4; ++fm) {
                int row = wm * 64 + fm * 16 + ln15;
                int p = (kq * 4 + qd) ^ (row & 7);
                af[fm] = *(const bf16x8*)&As[row * GBK + p * 8];
            }
#pragma unroll
            for (int fn = 0; fn < 4; ++fn) {
                int row = wn * 64 + fn * 16 + ln15;
                int p = (kq * 4 + qd) ^ (row & 7);
                bf[fn] = *(const bf16x8*)&Bs[row * GBK + p * 8];
            }
#pragma unroll
            for (int fm = 0; fm < 4; ++fm)
#pragma unroll
                for (int fn = 0; fn < 4; ++fn)
                    acc[fm][fn] = __builtin_amdgcn_mfma_f32_16x16x32_bf16(
                        af[fm], bf[fn], acc[fm][fn], 0, 0, 0);
        }
        __syncthreads();
    }

    // epilogue: C/D row = qd*4+reg, col = ln15; accumulate via device atomics
#pragma unroll
    for (int fn = 0; fn < 4; ++fn) {
        int o = o0 + wn * 64 + fn * 16 + ln15;
#pragma unroll
        for (int fm = 0; fm < 4; ++fm) {
            int r0 = m0 + wm * 64 + fm * 16 + qd * 4;
#pragma unroll
            for (int r = 0; r < 4; ++r)
                atomicAdd(&out[(size_t)(r0 + r) * OUT_FEAT + o], acc[fm][fn][r]);
        }
    }
}

// ---------------- fallback fused GEMM (round-1, used if ws too small) ----------------
#define BM 128
#define BN 64
#define BK 64
#define LDA 72
#define LDB 72

__global__ __launch_bounds__(256) void kan_gemm_fused(
    const float* __restrict__ x, const short* __restrict__ Wb,
    const float* __restrict__ bias, float* __restrict__ out)
{
    __shared__ __align__(16) short Asf[BM * LDA];
    __shared__ __align__(16) short Bsf[BN * LDB];

    int tid = threadIdx.x;
    int mb = blockIdx.x >> 3;
    int nb = blockIdx.x & 7;
    int m0 = mb * BM, o0 = nb * BN;

    int lane = tid & 63, wv = tid >> 6;
    int wm = wv >> 1, wn = wv & 1;
    int qd = lane >> 4, ln15 = lane & 15;

    f32x4 acc[4][2];
#pragma unroll
    for (int a = 0; a < 4; ++a)
#pragma unroll
        for (int b = 0; b < 2; ++b) acc[a][b] = (f32x4)0.f;

    int n_local = tid >> 1;
    int half = tid & 1;
    const float4* xrow = (const float4*)(x + (size_t)(m0 + n_local) * IN_FEAT);

    for (int it = 0; it < IN_FEAT / 8; ++it) {
        float4 xv = xrow[it * 2 + half];
        float xs[4] = {xv.x, xv.y, xv.z, xv.w};
#pragma unroll
        for (int ii = 0; ii < 4; ++ii) {
            float xc = fminf(fmaxf(xs[ii], -1.f), 1.f);
            float base = xc / (1.f + __expf(-xc));
            bf16x8 fr;
            fr[0] = f2bf(base);
            float t = xc;
            fr[1] = f2bf(t);
#pragma unroll
            for (int f = 2; f < 8; ++f) { t = 2.f * xc * t - 1.f; fr[f] = f2bf(t); }
            *(bf16x8*)&Asf[n_local * LDA + half * 32 + ii * 8] = fr;
        }
#pragma unroll
        for (int rep = 0; rep < 2; ++rep) {
            int c = tid + rep * 256;
            int row = c >> 3, cc = c & 7;
            bf16x8 wfrag = *(const bf16x8*)(Wb + (size_t)(o0 + row) * KDIM + it * BK + cc * 8);
            *(bf16x8*)&Bsf[row * LDB + cc * 8] = wfrag;
        }
        __syncthreads();
#pragma unroll
        for (int kq = 0; kq < 2; ++kq) {
            bf16x8 af[4], bfr[2];
#pragma unroll
            for (int fm = 0; fm < 4; ++fm)
                af[fm] = *(const bf16x8*)&Asf[(wm * 64 + fm * 16 + ln15) * LDA + kq * 32 + qd * 8];
#pragma unroll
            for (int fn = 0; fn < 2; ++fn)
                bfr[fn] = *(const bf16x8*)&Bsf[(wn * 32 + fn * 16 + ln15) * LDB + kq * 32 + qd * 8];
#pragma unroll
            for (int fm = 0; fm < 4; ++fm)
#pragma unroll
                for (int fn = 0; fn < 2; ++fn)
                    acc[fm][fn] = __builtin_amdgcn_mfma_f32_16x16x32_bf16(
                        af[fm], bfr[fn], acc[fm][fn], 0, 0, 0);
        }
        __syncthreads();
    }

#pragma unroll
    for (int fn = 0; fn < 2; ++fn) {
        int o = o0 + wn * 32 + fn * 16 + ln15;
        float bv = bias[o];
#pragma unroll
        for (int fm = 0; fm < 4; ++fm) {
            int r0 = m0 + wm * 64 + fm * 16 + qd * 4;
#pragma unroll
            for (int r = 0; r < 4; ++r)
                out[(size_t)(r0 + r) * OUT_FEAT + o] = acc[fm][fn][r] + bv;
        }
    }
}

extern "C" void kernel_launch(void* const* d_in, const int* in_sizes, int n_in,
                              void* d_out, int out_size, void* d_ws, size_t ws_size,
                              hipStream_t stream) {
    const float* x            = (const float*)d_in[0];
    const float* coeff        = (const float*)d_in[1];
    const float* scale_base   = (const float*)d_in[2];
    const float* scale_spline = (const float*)d_in[3];
    const float* base_bias    = (const float*)d_in[4];
    float* out = (float*)d_out;

    const size_t WB_BYTES   = (size_t)OUT_FEAT * KDIM * 2;       // 4 MB
    const size_t BIAS_OFF   = WB_BYTES;                          // +2 KB (pad to 64 KB)
    const size_t A_OFF      = WB_BYTES + 65536;
    const size_t A_BYTES    = (size_t)NTOK * KDIM * 2;           // 64 MB
    short* Wb   = (short*)d_ws;
    float* bias = (float*)((char*)d_ws + BIAS_OFF);

    kan_prep<<<OUT_FEAT, 256, 0, stream>>>(coeff, scale_base, scale_spline, base_bias, Wb, bias);

    if (ws_size >= A_OFF + A_BYTES) {
        short* A = (short*)((char*)d_ws + A_OFF);
        kan_agen<<<NTOK * IN_FEAT / 256, 256, 0, stream>>>(x, A);
        kan_init_out<<<NTOK * OUT_FEAT / 4 / 256, 256, 0, stream>>>(bias, out);
        dim3 grid(OUT_FEAT / GBN, NTOK / GBM, 2);   // nb fastest for L2 reuse of A-tiles
        kan_gemm2<<<grid, 256, 0, stream>>>(A, Wb, out);
    } else {
        kan_gemm_fused<<<(NTOK / BM) * (OUT_FEAT / BN), 256, 0, stream>>>(x, Wb, bias, out);
    }
}

// Round 3
// 145.428 us; speedup vs baseline: 1.1046x; 1.1046x over previous
//
#include <hip/hip_runtime.h>
#include <hip/hip_bf16.h>

// KAN linear, fused: out[n,o] = silu(xc)·scale_base + Σ_k basis_k·(scale_spline·coeff_k) + bias
// == GEMM M=8192, N=512, K=4096 (8 feats/input, basis_0 folded into bias).
// A generated in-register -> LDS (never hits HBM). W prepped once (4 MB bf16).
#define IN_FEAT 512
#define OUT_FEAT 512
#define NTOK 8192
#define KDIM 4096

#define BM 64
#define BN 128
#define BK 64          // 8 inputs x 8 basis feats per K-iter

typedef short bf16x8 __attribute__((ext_vector_type(8)));
typedef float f32x4 __attribute__((ext_vector_type(4)));

static __device__ inline short f2bf(float f) {
    union { float f; unsigned u; } v; v.f = f;
    unsigned u = v.u;
    u += 0x7fffu + ((u >> 16) & 1u);   // RNE
    return (short)(u >> 16);
}

// pack two fp32 -> bf16 pair (round-half-up) in ~3 VALU: 2 adds + v_perm
static __device__ inline unsigned pack2bf(float f0, float f1) {
    union { float f; unsigned u; } a, b; a.f = f0; b.f = f1;
    return __builtin_amdgcn_perm(b.u + 0x8000u, a.u + 0x8000u, 0x07060302u);
}

static __device__ inline void gload_lds16(const short* g, short* l) {
    __builtin_amdgcn_global_load_lds(
        (const __attribute__((address_space(1))) unsigned int*)g,
        (__attribute__((address_space(3))) unsigned int*)l,
        16, 0, 0);
}

// ---------------- prep: W bf16 [512 x 4096] + folded bias ----------------
__global__ __launch_bounds__(256) void kan_prep(
    const float* __restrict__ coeff, const float* __restrict__ scale_base,
    const float* __restrict__ scale_spline, const float* __restrict__ base_bias,
    short* __restrict__ Wb, float* __restrict__ bias)
{
    int o = blockIdx.x;
    int tid = threadIdx.x;
    float local = 0.f;
#pragma unroll
    for (int rep = 0; rep < 2; ++rep) {
        int i = tid + rep * 256;
        size_t oi = (size_t)o * IN_FEAT + i;
        const float4* c4 = (const float4*)(coeff + oi * 8);
        float4 ca = c4[0], cb = c4[1];
        float ss = scale_spline[oi];
        float sb = scale_base[oi];
        local += base_bias[oi] + ss * ca.x;
        bf16x8 w;
        w[0] = f2bf(sb);
        w[1] = f2bf(ss * ca.y); w[2] = f2bf(ss * ca.z); w[3] = f2bf(ss * ca.w);
        w[4] = f2bf(ss * cb.x); w[5] = f2bf(ss * cb.y); w[6] = f2bf(ss * cb.z);
        w[7] = f2bf(ss * cb.w);
        *(bf16x8*)(Wb + (size_t)o * KDIM + (size_t)i * 8) = w;
    }
    __shared__ float red[4];
    for (int off = 32; off > 0; off >>= 1) local += __shfl_down(local, off, 64);
    int lane = tid & 63, wv = tid >> 6;
    if (lane == 0) red[wv] = local;
    __syncthreads();
    if (tid == 0) bias[o] = red[0] + red[1] + red[2] + red[3];
}

// ---------------- fused GEMM: double-buffered LDS, 1 barrier/iter ----------------
// LDS layout (both A and B): row r, logical 16B chunk c stored at phys chunk c^(r&7).
__global__ __launch_bounds__(256) void kan_gemm3(
    const float* __restrict__ x, const short* __restrict__ Wb,
    const float* __restrict__ bias, float* __restrict__ out)
{
    __shared__ __align__(16) short As[2][BM * BK];   // 2 x 8 KB
    __shared__ __align__(16) short Bs[2][BN * BK];   // 2 x 16 KB

    int tid = threadIdx.x;
    int nb = blockIdx.x & 3;         // nb fastest -> x rows shared across nb hit L2
    int mb = blockIdx.x >> 2;
    int m0 = mb * BM, o0 = nb * BN;

    int lane = tid & 63, wv = tid >> 6;
    int wm = wv & 1, wn = wv >> 1;   // wave tile 32 x 64
    int qd = lane >> 4, ln15 = lane & 15;

    f32x4 acc[2][4];
#pragma unroll
    for (int a = 0; a < 2; ++a)
#pragma unroll
        for (int b = 0; b < 4; ++b) acc[a][b] = (f32x4)0.f;

    // ---- A-gen assignment: thread -> (token, input-pair) ----
    int tok = tid >> 2;              // 0..63
    int c0  = (tid & 3) * 2;         // input chunk pair c0, c0+1
    const float2* xp = (const float2*)(x + (size_t)(m0 + tok) * IN_FEAT) + (tid & 3);

    // ---- B DMA assignment: wave wv stages rows [wv*32, wv*32+32) ----
    int rg = lane >> 3;              // row-in-group 0..7
    int c_log = (lane & 7) ^ rg;     // logical chunk fetched so phys=lane&7 is swizzled
    const short* Bg = Wb + (size_t)(o0 + wv * 32 + rg) * KDIM + c_log * 8;

    // generate A chunk (8 basis feats of one input) from scalar x
#define GEN_CHUNK(xval, cc, buf)                                              \
    {                                                                         \
        float xc = fminf(fmaxf((xval), -1.f), 1.f);                           \
        float bse = xc / (1.f + __expf(-xc));                                 \
        float b2 = 2.f * xc * xc - 1.f;                                       \
        float b3 = 2.f * xc * b2 - 1.f;                                       \
        float b4 = 2.f * xc * b3 - 1.f;                                       \
        float b5 = 2.f * xc * b4 - 1.f;                                       \
        float b6 = 2.f * xc * b5 - 1.f;                                       \
        float b7 = 2.f * xc * b6 - 1.f;                                       \
        uint4 pk;                                                             \
        pk.x = pack2bf(bse, xc); pk.y = pack2bf(b2, b3);                      \
        pk.z = pack2bf(b4, b5);  pk.w = pack2bf(b6, b7);                      \
        *(uint4*)&As[buf][tok * BK + ((cc) ^ (tok & 7)) * 8] = pk;            \
    }

    // ---- prologue: stage iter 0 ----
    {
        float2 xv = xp[0];
        GEN_CHUNK(xv.x, c0, 0);
        GEN_CHUNK(xv.y, c0 + 1, 0);
#pragma unroll
        for (int j = 0; j < 4; ++j)
            gload_lds16(Bg + (size_t)j * 8 * KDIM, &Bs[0][(wv * 32 + j * 8) * BK]);
    }

    int cur = 0;
    for (int it = 0; it < IN_FEAT / 8; ++it, cur ^= 1) {
        __syncthreads();             // drains DMA (vmcnt) + ds_writes (lgkm) for iter `it`
        if (it < IN_FEAT / 8 - 1) {
            int nxt = cur ^ 1;
#pragma unroll
            for (int j = 0; j < 4; ++j)
                gload_lds16(Bg + (it + 1) * BK + (size_t)j * 8 * KDIM,
                            &Bs[nxt][(wv * 32 + j * 8) * BK]);
            float2 xv = xp[(it + 1) * 4];
            GEN_CHUNK(xv.x, c0, nxt);
            GEN_CHUNK(xv.y, c0 + 1, nxt);
        }
        // ---- MFMA on buffer `cur` ----
#pragma unroll
        for (int kq = 0; kq < 2; ++kq) {
            bf16x8 af[2], bf[4];
#pragma unroll
            for (int fm = 0; fm < 2; ++fm) {
                int row = wm * 32 + fm * 16 + ln15;
                af[fm] = *(const bf16x8*)&As[cur][row * BK + ((kq * 4 + qd) ^ (row & 7)) * 8];
            }
#pragma unroll
            for (int fn = 0; fn < 4; ++fn) {
                int row = wn * 64 + fn * 16 + ln15;
                bf[fn] = *(const bf16x8*)&Bs[cur][row * BK + ((kq * 4 + qd) ^ (row & 7)) * 8];
            }
#pragma unroll
            for (int fm = 0; fm < 2; ++fm)
#pragma unroll
                for (int fn = 0; fn < 4; ++fn)
                    acc[fm][fn] = __builtin_amdgcn_mfma_f32_16x16x32_bf16(
                        af[fm], bf[fn], acc[fm][fn], 0, 0, 0);
        }
    }

    // ---- epilogue: C/D row = qd*4+reg, col = ln15 ----
#pragma unroll
    for (int fn = 0; fn < 4; ++fn) {
        int o = o0 + wn * 64 + fn * 16 + ln15;
        float bv = bias[o];
#pragma unroll
        for (int fm = 0; fm < 2; ++fm) {
            int r0 = m0 + wm * 32 + fm * 16 + qd * 4;
#pragma unroll
            for (int r = 0; r < 4; ++r)
                out[(size_t)(r0 + r) * OUT_FEAT + o] = acc[fm][fn][r] + bv;
        }
    }
#undef GEN_CHUNK
}

extern "C" void kernel_launch(void* const* d_in, const int* in_sizes, int n_in,
                              void* d_out, int out_size, void* d_ws, size_t ws_size,
                              hipStream_t stream) {
    const float* x            = (const float*)d_in[0];
    const float* coeff        = (const float*)d_in[1];
    const float* scale_base   = (const float*)d_in[2];
    const float* scale_spline = (const float*)d_in[3];
    const float* base_bias    = (const float*)d_in[4];
    float* out = (float*)d_out;

    short* Wb   = (short*)d_ws;                                  // 4 MB
    float* bias = (float*)((char*)d_ws + (size_t)OUT_FEAT * KDIM * 2);

    kan_prep<<<OUT_FEAT, 256, 0, stream>>>(coeff, scale_base, scale_spline, base_bias, Wb, bias);
    kan_gemm3<<<(NTOK / BM) * (OUT_FEAT / BN), 256, 0, stream>>>(x, Wb, bias, out);
}